// Round 6
// baseline (9612.453 us; speedup 1.0000x reference)
//
#include <hip/hip_runtime.h>
#include <math.h>

// Problem constants (fixed by reference setup_inputs)
#define RS 3072   // B*CH signals
#define NF 2048   // signal length N
#define MS 512    // measurements M

typedef _Float16 f16;
typedef _Float16 f16x4 __attribute__((ext_vector_type(4)));
typedef _Float16 f16x8 __attribute__((ext_vector_type(8)));
typedef float f32x4 __attribute__((ext_vector_type(4)));

// idxs may be int64 (pairs [lo,0]) or int32; sorted-unique => idxs[1] >= 1.
__device__ __forceinline__ int load_idx(const int* p, int j) {
    return (p[1] == 0) ? p[2 * j] : p[j];
}

#define PI_OVER_4096 7.669903939428206e-4f
#define CK0 0.022097086912079608f  // sqrt(1/2048)
#define CKN 0.03125f               // sqrt(2/2048)

// Wg[j][k] = A[j,k] (512x2048, k-contig);  Wh[n][j] = A[j,n] (2048x512, j-contig)
__global__ void build_w_kernel(const int* idxs, f16* Wg, f16* Wh) {
    int t = blockIdx.x * 256 + threadIdx.x;   // over MS*NF
    int j = t >> 11, k = t & (NF - 1);
    int ii = load_idx(idxs, j);
    float ck = (k == 0) ? CK0 : CKN;
    int ph = ((2 * ii + 1) * k) & 8191;
    float v = ck * cosf((float)ph * PI_OVER_4096);
    Wg[(size_t)j * NF + k] = (f16)v;
    Wh[(size_t)k * MS + j] = (f16)v;
}

// Dg[i][k] = IDCT[i,k] = c_k cos(pi*(2i+1)k/4096)  (2048x2048, k-contig)
__global__ void build_d_kernel(f16* Dg) {
    int t = blockIdx.x * 256 + threadIdx.x;   // over NF*NF
    int i = t >> 11, k = t & (NF - 1);
    float ck = (k == 0) ? CK0 : CKN;
    int ph = ((2 * i + 1) * k) & 8191;
    Dg[(size_t)i * NF + k] = (f16)(ck * cosf((float)ph * PI_OVER_4096));
}

// Bm[r][j] = x[r, idxs[j]]  (UNSCALED; c = 100*acc in epilogue)
__global__ void build_b_kernel(const float* x, const int* idxs, f16* Bm) {
    int t = blockIdx.x * 256 + threadIdx.x;   // over RS*MS
    int r = t >> 9, j = t & (MS - 1);
    Bm[t] = (f16)(x[(size_t)r * NF + load_idx(idxs, j)]);
}

// H = clamp(20*(v+c), -1, 1) in f16 — single definition shared by phase-1
// staging and phase-2 epilogue so both round identically (proven numerics).
__device__ __forceinline__ f16 hclamp(f16 v, f16 c) {
    f16 s = (f16)((v + c) * (f16)20.0);
    s = s > (f16)1.0 ? (f16)1.0 : s;
    s = s < (f16)-1.0 ? (f16)-1.0 : s;
    return s;
}

// GEMM acc[u][r] = sum_k A[u][k]*B[r][k], 64x64 wave tiles (2x2 waves, 128x128
// block). A-fragments come DIRECTLY from global (k-contig rows match the MFMA
// A layout: lane ln <- row m=ln, 16B at k=q*8) — W/Dg panels are L2-resident,
// so A rides the VMEM pipe and LDS carries only B (double-buffered pipeline,
// padded stride => <=2-way conflicts). Per-stage order: A-frag loads first,
// then B prefetch, so vmcnt waits on A don't drain the younger B prefetch.
// MODE 0: c = 100*acc; v = 0              (A=Wh, B=Bm)
// MODE 1: Y = acc                         (A=Wg, B=H(v,c) clamped in regs)
// MODE 2: v += 0.05*(acc - H(v,c))        (A=Wh, B=Y)
// MODE 3: MODE2 then store F' = g - 0.05*clip(20g), g = v_new + c
// MODE 4: out = 0.01*acc (f32)            (A=Dg, B=F')
template<int BK, int KT, int NP, int RPX, int LNP, int GRP, int MODE>
__global__ __launch_bounds__(256) void gemm_g(
    const f16* __restrict__ A, const f16* __restrict__ B,
    const f16* __restrict__ vb, const f16* __restrict__ cb,
    f16* __restrict__ o16, f16* __restrict__ o16b,
    float* __restrict__ outF, int ldo)
{
    constexpr int BU = 128, BR = 128, WU = 64, WR = 64;
    constexpr int IM = 4, IN = 4;
    constexpr int SA = BK + 8;            // padded LDS row stride (f16)
    constexpr int CPR = BK / 8;           // f16x8 chunks per row
    constexpr int RPP = 256 / CPR;        // rows staged per pass
    constexpr int PB = BR / RPP;
    constexpr int NS = KT / BK;
    constexpr int KS = BK / 32;

    __shared__ __align__(16) f16 Bs[2 * BR * SA];

    const int tid = threadIdx.x;
    const int w = tid >> 6, l = tid & 63;
    const int wr = w >> 1, wc = w & 1;
    const int q = l >> 4, ln = l & 15;
    const int trow = tid / CPR, tch = tid % CPR;

    const int blk = blockIdx.x, xcd = blk & 7, local = blk >> 3;
    int up, rp;
    if constexpr (GRP == 0) { up = local & (NP - 1); rp = xcd * RPX + (local >> LNP); }
    else                    { up = xcd * NP + (local & (NP - 1)); rp = local >> LNP; }
    const int bu = up * BU, br = rp * BR;

    f32x4 acc[IM][IN];
#pragma unroll
    for (int a = 0; a < IM; ++a)
#pragma unroll
        for (int b = 0; b < IN; ++b)
            acc[a][b] = (f32x4){0.f, 0.f, 0.f, 0.f};

    // per-thread A row pointers (global, k-contig)
    const f16* Aptr[IM];
#pragma unroll
    for (int im = 0; im < IM; ++im)
        Aptr[im] = A + (size_t)(bu + wr * WU + im * 16 + ln) * KT + q * 8;

    const f16* Bb = (MODE == 1) ? (const f16*)nullptr : B + (size_t)br * KT;

    f16x8 rB[PB], rC[(MODE == 1) ? PB : 1];

    auto load_B = [&](int s) {
        if constexpr (MODE == 1) {
#pragma unroll
            for (int p = 0; p < PB; ++p) {
                const size_t go = (size_t)(br + p * RPP + trow) * NF + s * BK + tch * 8;
                rB[p] = *(const f16x8*)(vb + go);
                rC[p] = *(const f16x8*)(cb + go);
            }
        } else {
#pragma unroll
            for (int p = 0; p < PB; ++p)
                rB[p] = *(const f16x8*)(Bb + (size_t)(p * RPP + trow) * KT + s * BK + tch * 8);
        }
    };
    auto write_B = [&](int buf) {
        f16* Bd = Bs + buf * BR * SA + trow * SA + tch * 8;
        if constexpr (MODE == 1) {
#pragma unroll
            for (int p = 0; p < PB; ++p) {
                f16x8 z;
#pragma unroll
                for (int e = 0; e < 8; ++e) z[e] = hclamp(rB[p][e], rC[p][e]);
                *(f16x8*)(Bd + p * RPP * SA) = z;
            }
        } else {
#pragma unroll
            for (int p = 0; p < PB; ++p)
                *(f16x8*)(Bd + p * RPP * SA) = rB[p];
        }
    };

    load_B(0);
    write_B(0);
    __syncthreads();

    for (int s = 0; s < NS; ++s) {
        // A fragments for this stage — issued BEFORE the B prefetch
        f16x8 af[IM][KS];
#pragma unroll
        for (int im = 0; im < IM; ++im)
#pragma unroll
            for (int ks = 0; ks < KS; ++ks)
                af[im][ks] = *(const f16x8*)(Aptr[im] + s * BK + ks * 32);
        if (s + 1 < NS) load_B(s + 1);        // younger: stays in flight
        const f16* Br = Bs + (s & 1) * BR * SA;
#pragma unroll
        for (int ks = 0; ks < KS; ++ks) {
            f16x8 bf[IN];
#pragma unroll
            for (int in = 0; in < IN; ++in)
                bf[in] = *(const f16x8*)(Br + (wc * WR + in * 16 + ln) * SA + ks * 32 + q * 8);
#pragma unroll
            for (int im = 0; im < IM; ++im)
#pragma unroll
                for (int in = 0; in < IN; ++in)
                    acc[im][in] = __builtin_amdgcn_mfma_f32_16x16x32_f16(
                        af[im][ks], bf[in], acc[im][in], 0, 0, 0);
        }
        if (s + 1 < NS) write_B((s + 1) & 1);
        __syncthreads();
    }

    // epilogue: C/D layout col(lane&15)=r-frag, row(q*4+reg)=u-frag (contig)
#pragma unroll
    for (int im = 0; im < IM; ++im) {
#pragma unroll
        for (int in = 0; in < IN; ++in) {
            const int u0 = bu + wr * WU + im * 16 + q * 4;
            const int r0 = br + wc * WR + in * 16 + ln;
            const size_t off = (size_t)r0 * ldo + u0;
            f32x4 a4 = acc[im][in];
            if constexpr (MODE == 0) {
                f16x4 cc, zz;
#pragma unroll
                for (int e = 0; e < 4; ++e) { cc[e] = (f16)(100.0f * a4[e]); zz[e] = (f16)0.0; }
                *(f16x4*)(o16 + off) = cc;
                *(f16x4*)(o16b + off) = zz;
            } else if constexpr (MODE == 1) {
                f16x4 yy;
#pragma unroll
                for (int e = 0; e < 4; ++e) yy[e] = (f16)a4[e];
                *(f16x4*)(o16 + off) = yy;
            } else if constexpr (MODE == 2 || MODE == 3) {
                f16x4 v4 = *(const f16x4*)(vb + off);
                f16x4 c4 = *(const f16x4*)(cb + off);
                f16x4 st;
#pragma unroll
                for (int e = 0; e < 4; ++e) {
                    f16 hz = hclamp(v4[e], c4[e]);            // == phase-1 operand
                    float vn = (float)v4[e] + 0.05f * (a4[e] - (float)hz);
                    if constexpr (MODE == 2) {
                        st[e] = (f16)vn;
                    } else {
                        float g = vn + (float)c4[e];          // F' = g - 0.05*h100
                        float zf = fminf(fmaxf(20.0f * g, -1.f), 1.f);
                        st[e] = (f16)(g - 0.05f * zf);
                    }
                }
                *(f16x4*)(o16 + off) = st;
            } else {
                f32x4 ov;
#pragma unroll
                for (int e = 0; e < 4; ++e) ov[e] = 0.01f * a4[e];
                *(f32x4*)(outF + off) = ov;
            }
        }
    }
}

extern "C" void kernel_launch(void* const* d_in, const int* in_sizes, int n_in,
                              void* d_out, int out_size, void* d_ws, size_t ws_size,
                              hipStream_t stream) {
    const float* x = (const float*)d_in[0];
    const int* idxs = (const int*)d_in[1];

    // Workspace: round-2's proven ~32.8 MB envelope.
    // Dg (8 MB) aliases Wg|Wh|BmY|c16-head — all dead before build_d runs.
    char* p = (char*)d_ws;
    auto take = [&](size_t n) { char* q = p; p += (n + 255) & ~(size_t)255; return q; };
    f16* Wg  = (f16*)take((size_t)MS * NF * 2);   // 2 MB
    f16* Wh  = (f16*)take((size_t)NF * MS * 2);   // 2 MB
    f16* BmY = (f16*)take((size_t)RS * MS * 2);   // 3 MB   Bm, then Y
    f16* c16 = (f16*)take((size_t)RS * NF * 2);   // 12.6 MB
    f16* v16 = (f16*)take((size_t)RS * NF * 2);   // 12.6 MB  v, then F'
    f16* Dg  = (f16*)d_ws;                        // aliased idct matrix

    build_w_kernel<<<dim3(MS * NF / 256), 256, 0, stream>>>(idxs, Wg, Wh);
    build_b_kernel<<<dim3(RS * MS / 256), 256, 0, stream>>>(x, idxs, BmY);

    // c = 100*Bm@A; v = 0   (u=n 16 panels x r 24 panels, K=512, 384 blocks)
    gemm_g<64, 512, 16, 3, 4, 0, 0><<<dim3(384), 256, 0, stream>>>(
        Wh, BmY, nullptr, nullptr, c16, v16, nullptr, NF);

    // 99 iterations
    for (int it = 0; it < 99; ++it) {
        // Y = Wg @ H(v,c)   (u=j 4 panels x r 24, K=2048, 96 blocks)
        gemm_g<64, 2048, 4, 3, 2, 0, 1><<<dim3(96), 256, 0, stream>>>(
            Wg, nullptr, v16, c16, BmY, nullptr, nullptr, MS);
        // v += 0.05*(Wh@Y - H)   (u=n 16 x r 24, K=512, 384 blocks)
        if (it < 98)
            gemm_g<64, 512, 16, 3, 4, 0, 2><<<dim3(384), 256, 0, stream>>>(
                Wh, BmY, v16, c16, v16, nullptr, nullptr, NF);
        else
            gemm_g<64, 512, 16, 3, 4, 0, 3><<<dim3(384), 256, 0, stream>>>(
                Wh, BmY, v16, c16, v16, nullptr, nullptr, NF);
    }

    // out = 0.01 * F' @ D   (u=i 16 x r 24, K=2048, 384 blocks; Dg panels
    // pinned per XCD via GRP=1 so A stays L2-resident)
    build_d_kernel<<<dim3(NF * NF / 256), 256, 0, stream>>>(Dg);
    gemm_g<64, 2048, 2, 0, 1, 1, 4><<<dim3(384), 256, 0, stream>>>(
        Dg, v16, nullptr, nullptr, nullptr, nullptr, (float*)d_out, NF);
}

// Round 7
// 6030.210 us; speedup vs baseline: 1.5940x; 1.5940x over previous
//
#include <hip/hip_runtime.h>
#include <math.h>

// Problem constants (fixed by reference setup_inputs)
#define RS 3072   // B*CH signals
#define NF 2048   // signal length N
#define MS 512    // measurements M

typedef _Float16 f16;
typedef _Float16 f16x4 __attribute__((ext_vector_type(4)));
typedef _Float16 f16x8 __attribute__((ext_vector_type(8)));
typedef float f32x4 __attribute__((ext_vector_type(4)));

// idxs may be int64 (pairs [lo,0]) or int32; sorted-unique => idxs[1] >= 1.
__device__ __forceinline__ int load_idx(const int* p, int j) {
    return (p[1] == 0) ? p[2 * j] : p[j];
}

#define PI_OVER_4096 7.669903939428206e-4f
#define CK0 0.022097086912079608f  // sqrt(1/2048)
#define CKN 0.03125f               // sqrt(2/2048)

// Fused: Wg[j][k]=A[j,k] (512x2048), Wh[n][j]=A[j,n] (2048x512), Bm[r][j]=x[r,idxs[j]]
__global__ void build_wb(const int* idxs, const float* x, f16* Wg, f16* Wh, f16* Bm) {
    int t = blockIdx.x * 256 + threadIdx.x;   // grid covers RS*MS exactly
    if (t < MS * NF) {
        int j = t >> 11, k = t & (NF - 1);
        int ii = load_idx(idxs, j);
        float ck = (k == 0) ? CK0 : CKN;
        int ph = ((2 * ii + 1) * k) & 8191;
        float v = ck * cosf((float)ph * PI_OVER_4096);
        Wg[(size_t)j * NF + k] = (f16)v;
        Wh[(size_t)k * MS + j] = (f16)v;
    }
    {
        int r = t >> 9, j = t & (MS - 1);
        Bm[t] = (f16)(x[(size_t)r * NF + load_idx(idxs, j)]);
    }
}

// Dg[i][k] = IDCT[i,k] = c_k cos(pi*(2i+1)k/4096)  (2048x2048, k-contig)
__global__ void build_d_kernel(f16* Dg) {
    int t = blockIdx.x * 256 + threadIdx.x;   // over NF*NF
    int i = t >> 11, k = t & (NF - 1);
    float ck = (k == 0) ? CK0 : CKN;
    int ph = ((2 * i + 1) * k) & 8191;
    Dg[(size_t)i * NF + k] = (f16)(ck * cosf((float)ph * PI_OVER_4096));
}

// H = clamp(20*(v+c), -1, 1) in f16 — single definition shared by phase-1
// staging and phase-2 epilogue so both round identically (proven numerics).
__device__ __forceinline__ f16 hclamp(f16 v, f16 c) {
    f16 s = (f16)((v + c) * (f16)20.0);
    s = s > (f16)1.0 ? (f16)1.0 : s;
    s = s < (f16)-1.0 ? (f16)-1.0 : s;
    return s;
}

// ---------------- R5 pipelined GEMM (proven) for c-build and final idct ----
// MODE 0: c = 100*acc; v = 0              (A=Wh, B=Bm)
// MODE 4: out = 0.01*acc (f32)            (A=Dg, B=F')
template<int BU, int BR, int BK, int KT, int NP, int RPX, int LNP, int GRP, int MODE>
__global__ __launch_bounds__(256) void gemm_p(
    const f16* __restrict__ A, const f16* __restrict__ B,
    const f16* __restrict__ vb, const f16* __restrict__ cb,
    f16* __restrict__ o16, f16* __restrict__ o16b,
    float* __restrict__ outF, int ldo)
{
    constexpr int WU = BU / 2, WR = BR / 2;
    constexpr int IM = WU / 16, IN = WR / 16;
    constexpr int SA = BK + 8;
    constexpr int CPR = BK / 8;
    constexpr int RPP = 256 / CPR;
    constexpr int PA = BU / RPP, PB = BR / RPP;
    constexpr int NS = KT / BK;

    __shared__ __align__(16) f16 As[2 * BU * SA];
    __shared__ __align__(16) f16 Bs[2 * BR * SA];

    const int tid = threadIdx.x;
    const int w = tid >> 6, l = tid & 63;
    const int wr = w >> 1, wc = w & 1;
    const int q = l >> 4, ln = l & 15;
    const int trow = tid / CPR, tch = tid % CPR;

    const int blk = blockIdx.x, xcd = blk & 7, local = blk >> 3;
    int up, rp;
    if constexpr (GRP == 0) { up = local & (NP - 1); rp = xcd * RPX + (local >> LNP); }
    else                    { up = xcd * NP + (local & (NP - 1)); rp = local >> LNP; }
    const int bu = up * BU, br = rp * BR;

    f32x4 acc[IM][IN];
#pragma unroll
    for (int a = 0; a < IM; ++a)
#pragma unroll
        for (int b = 0; b < IN; ++b)
            acc[a][b] = (f32x4){0.f, 0.f, 0.f, 0.f};

    const f16* Ab = A + (size_t)bu * KT;
    const f16* Bb = B + (size_t)br * KT;

    f16x8 rA[PA], rB[PB];
    auto load_stage = [&](int s) {
#pragma unroll
        for (int p = 0; p < PA; ++p)
            rA[p] = *(const f16x8*)(Ab + (size_t)(p * RPP + trow) * KT + s * BK + tch * 8);
#pragma unroll
        for (int p = 0; p < PB; ++p)
            rB[p] = *(const f16x8*)(Bb + (size_t)(p * RPP + trow) * KT + s * BK + tch * 8);
    };
    auto write_stage = [&](int buf) {
        f16* Ad = As + buf * BU * SA + trow * SA + tch * 8;
        f16* Bd = Bs + buf * BR * SA + trow * SA + tch * 8;
#pragma unroll
        for (int p = 0; p < PA; ++p) *(f16x8*)(Ad + p * RPP * SA) = rA[p];
#pragma unroll
        for (int p = 0; p < PB; ++p) *(f16x8*)(Bd + p * RPP * SA) = rB[p];
    };

    load_stage(0);
    write_stage(0);
    __syncthreads();

    for (int s = 0; s < NS; ++s) {
        if (s + 1 < NS) load_stage(s + 1);
        const f16* Ar = As + (s & 1) * BU * SA;
        const f16* Br = Bs + (s & 1) * BR * SA;
#pragma unroll
        for (int ks = 0; ks < BK / 32; ++ks) {
            f16x8 af[IM], bf[IN];
#pragma unroll
            for (int im = 0; im < IM; ++im)
                af[im] = *(const f16x8*)(Ar + (wr * WU + im * 16 + ln) * SA + ks * 32 + q * 8);
#pragma unroll
            for (int in = 0; in < IN; ++in)
                bf[in] = *(const f16x8*)(Br + (wc * WR + in * 16 + ln) * SA + ks * 32 + q * 8);
#pragma unroll
            for (int im = 0; im < IM; ++im)
#pragma unroll
                for (int in = 0; in < IN; ++in)
                    acc[im][in] = __builtin_amdgcn_mfma_f32_16x16x32_f16(
                        af[im], bf[in], acc[im][in], 0, 0, 0);
        }
        if (s + 1 < NS) write_stage((s + 1) & 1);
        __syncthreads();
    }

#pragma unroll
    for (int im = 0; im < IM; ++im) {
#pragma unroll
        for (int in = 0; in < IN; ++in) {
            const int u0 = bu + wr * WU + im * 16 + q * 4;
            const int r0 = br + wc * WR + in * 16 + ln;
            const size_t off = (size_t)r0 * ldo + u0;
            f32x4 a4 = acc[im][in];
            if constexpr (MODE == 0) {
                f16x4 cc, zz;
#pragma unroll
                for (int e = 0; e < 4; ++e) { cc[e] = (f16)(100.0f * a4[e]); zz[e] = (f16)0.0; }
                *(f16x4*)(o16 + off) = cc;
                *(f16x4*)(o16b + off) = zz;
            } else {
                f32x4 ov;
#pragma unroll
                for (int e = 0; e < 4; ++e) ov[e] = 0.01f * a4[e];
                *(f32x4*)(outF + off) = ov;
            }
        }
    }
}

// ---------------- fused per-iteration kernel --------------------------------
// Phase 1 (blocks 0..383): Y[r64,j64] = Wg @ H(v,c); Y via LLC-coherent atomic
// stores; flag[rp*8+jp] += 1 after s_waitcnt(0)+barrier.
// Phase 2 (768 tiles over 512 blocks): wait r-panel's 8 flags >= ep, stream Y
// via atomic loads, v += 0.05*(Wh@Y - H). v/c/W use normal cached access —
// they never cross blocks inside a launch. No fences => no L2 invalidation.

__device__ __forceinline__ void dev_p1(
    int bu, int br, const f16* __restrict__ Wg,
    const f16* __restrict__ vb, const f16* __restrict__ cb,
    f16* Y, int* flagp, f16* As, f16* Bs)
{
    constexpr int KT = 2048, SA = 72, RPP = 32, NS = 32;   // 64x64 tile, BK=64
    const int tid = threadIdx.x;
    const int w = tid >> 6, l = tid & 63;
    const int wr = w >> 1, wc = w & 1;
    const int q = l >> 4, ln = l & 15;
    const int trow = tid >> 3, tch = tid & 7;

    f32x4 acc[2][2];
#pragma unroll
    for (int a = 0; a < 2; ++a)
#pragma unroll
        for (int b = 0; b < 2; ++b) acc[a][b] = (f32x4){0.f, 0.f, 0.f, 0.f};

    const f16* Ab = Wg + (size_t)bu * KT;
    f16x8 rA[2], rB[2], rC[2];
    auto load_stage = [&](int s) {
#pragma unroll
        for (int p = 0; p < 2; ++p)
            rA[p] = *(const f16x8*)(Ab + (size_t)(p * RPP + trow) * KT + s * 64 + tch * 8);
#pragma unroll
        for (int p = 0; p < 2; ++p) {
            const size_t go = (size_t)(br + p * RPP + trow) * NF + s * 64 + tch * 8;
            rB[p] = *(const f16x8*)(vb + go);
            rC[p] = *(const f16x8*)(cb + go);
        }
    };
    auto write_stage = [&](int buf) {
        f16* Ad = As + buf * 64 * SA + trow * SA + tch * 8;
        f16* Bd = Bs + buf * 64 * SA + trow * SA + tch * 8;
#pragma unroll
        for (int p = 0; p < 2; ++p) *(f16x8*)(Ad + p * RPP * SA) = rA[p];
#pragma unroll
        for (int p = 0; p < 2; ++p) {
            f16x8 z;
#pragma unroll
            for (int e = 0; e < 8; ++e) z[e] = hclamp(rB[p][e], rC[p][e]);
            *(f16x8*)(Bd + p * RPP * SA) = z;
        }
    };

    load_stage(0); write_stage(0); __syncthreads();
    for (int s = 0; s < NS; ++s) {
        if (s + 1 < NS) load_stage(s + 1);
        const f16* Ar = As + (s & 1) * 64 * SA;
        const f16* Br = Bs + (s & 1) * 64 * SA;
#pragma unroll
        for (int ks = 0; ks < 2; ++ks) {
            f16x8 af[2], bf[2];
#pragma unroll
            for (int im = 0; im < 2; ++im)
                af[im] = *(const f16x8*)(Ar + (wr * 32 + im * 16 + ln) * SA + ks * 32 + q * 8);
#pragma unroll
            for (int in = 0; in < 2; ++in)
                bf[in] = *(const f16x8*)(Br + (wc * 32 + in * 16 + ln) * SA + ks * 32 + q * 8);
#pragma unroll
            for (int im = 0; im < 2; ++im)
#pragma unroll
                for (int in = 0; in < 2; ++in)
                    acc[im][in] = __builtin_amdgcn_mfma_f32_16x16x32_f16(
                        af[im], bf[in], acc[im][in], 0, 0, 0);
        }
        if (s + 1 < NS) write_stage((s + 1) & 1);
        __syncthreads();
    }
    // Y[r][j] epilogue via write-through (LLC) dword atomic stores
#pragma unroll
    for (int im = 0; im < 2; ++im) {
#pragma unroll
        for (int in = 0; in < 2; ++in) {
            const int u0 = bu + wr * 32 + im * 16 + q * 4;
            const int r0 = br + wc * 32 + in * 16 + ln;
            union { f16x4 h; unsigned int u[2]; } cv;
#pragma unroll
            for (int e = 0; e < 4; ++e) cv.h[e] = (f16)acc[im][in][e];
            unsigned int* yp = (unsigned int*)(Y + (size_t)r0 * MS + u0);
            __hip_atomic_store(yp, cv.u[0], __ATOMIC_RELAXED, __HIP_MEMORY_SCOPE_AGENT);
            __hip_atomic_store(yp + 1, cv.u[1], __ATOMIC_RELAXED, __HIP_MEMORY_SCOPE_AGENT);
        }
    }
    __builtin_amdgcn_s_waitcnt(0);   // all this wave's Y stores at LLC
    __syncthreads();                 // => all waves' stores at LLC
    if (tid == 0)
        __hip_atomic_fetch_add(flagp, 1, __ATOMIC_RELAXED, __HIP_MEMORY_SCOPE_AGENT);
}

__device__ __forceinline__ void dev_p2(
    int bu, int br, const f16* __restrict__ Wh, const f16* Y,
    f16* __restrict__ vb, const f16* __restrict__ cb,
    int* flags, int ep, int last, f16* As, f16* Bs)
{
    constexpr int KT = 512, SA = 72, RPP = 32, NS = 8;   // 128x64 tile, BK=64
    const int tid = threadIdx.x;
    const int w = tid >> 6, l = tid & 63;
    const int wr = w >> 1, wc = w & 1;
    const int q = l >> 4, ln = l & 15;
    const int trow = tid >> 3, tch = tid & 7;

    f32x4 acc[4][2];
#pragma unroll
    for (int a = 0; a < 4; ++a)
#pragma unroll
        for (int b = 0; b < 2; ++b) acc[a][b] = (f32x4){0.f, 0.f, 0.f, 0.f};

    const f16* Ab = Wh + (size_t)bu * KT;
    f16x8 rA[4], rB[2];
    auto load_A = [&](int s) {
#pragma unroll
        for (int p = 0; p < 4; ++p)
            rA[p] = *(const f16x8*)(Ab + (size_t)(p * RPP + trow) * KT + s * 64 + tch * 8);
    };
    auto load_B = [&](int s) {
#pragma unroll
        for (int p = 0; p < 2; ++p) {
            const unsigned int* yp = (const unsigned int*)
                (Y + (size_t)(br + p * RPP + trow) * MS + s * 64 + tch * 8);
            union { f16x8 h; unsigned int u[4]; } cv;
#pragma unroll
            for (int d = 0; d < 4; ++d)
                cv.u[d] = __hip_atomic_load(yp + d, __ATOMIC_RELAXED, __HIP_MEMORY_SCOPE_AGENT);
            rB[p] = cv.h;
        }
    };
    auto write_stage = [&](int buf) {
        f16* Ad = As + buf * 128 * SA + trow * SA + tch * 8;
        f16* Bd = Bs + buf * 64 * SA + trow * SA + tch * 8;
#pragma unroll
        for (int p = 0; p < 4; ++p) *(f16x8*)(Ad + p * RPP * SA) = rA[p];
#pragma unroll
        for (int p = 0; p < 2; ++p) *(f16x8*)(Bd + p * RPP * SA) = rB[p];
    };

    load_A(0);                        // Wh prefetch overlaps the flag wait
    if (threadIdx.x < 8)
        while (__hip_atomic_load(&flags[threadIdx.x], __ATOMIC_RELAXED,
                                 __HIP_MEMORY_SCOPE_AGENT) < ep)
            __builtin_amdgcn_s_sleep(1);
    __syncthreads();                  // whole r-panel's Y is at LLC

    load_B(0); write_stage(0); __syncthreads();
    for (int s = 0; s < NS; ++s) {
        if (s + 1 < NS) { load_A(s + 1); load_B(s + 1); }
        const f16* Ar = As + (s & 1) * 128 * SA;
        const f16* Br = Bs + (s & 1) * 64 * SA;
#pragma unroll
        for (int ks = 0; ks < 2; ++ks) {
            f16x8 af[4], bf[2];
#pragma unroll
            for (int im = 0; im < 4; ++im)
                af[im] = *(const f16x8*)(Ar + (wr * 64 + im * 16 + ln) * SA + ks * 32 + q * 8);
#pragma unroll
            for (int in = 0; in < 2; ++in)
                bf[in] = *(const f16x8*)(Br + (wc * 32 + in * 16 + ln) * SA + ks * 32 + q * 8);
#pragma unroll
            for (int im = 0; im < 4; ++im)
#pragma unroll
                for (int in = 0; in < 2; ++in)
                    acc[im][in] = __builtin_amdgcn_mfma_f32_16x16x32_f16(
                        af[im], bf[in], acc[im][in], 0, 0, 0);
        }
        if (s + 1 < NS) write_stage((s + 1) & 1);
        __syncthreads();
    }
    // v-update epilogue (normal cached access; v/c private to launch boundary)
#pragma unroll
    for (int im = 0; im < 4; ++im) {
#pragma unroll
        for (int in = 0; in < 2; ++in) {
            const int u0 = bu + wr * 64 + im * 16 + q * 4;
            const int r0 = br + wc * 32 + in * 16 + ln;
            const size_t off = (size_t)r0 * NF + u0;
            f16x4 v4 = *(const f16x4*)(vb + off);
            f16x4 c4 = *(const f16x4*)(cb + off);
            f16x4 st;
#pragma unroll
            for (int e = 0; e < 4; ++e) {
                f16 hz = hclamp(v4[e], c4[e]);            // == phase-1 operand
                float vn = (float)v4[e] + 0.05f * (acc[im][in][e] - (float)hz);
                if (!last) {
                    st[e] = (f16)vn;
                } else {
                    float g = vn + (float)c4[e];          // F' = g - 0.05*h100
                    float zf = fminf(fmaxf(20.0f * g, -1.f), 1.f);
                    st[e] = (f16)(g - 0.05f * zf);
                }
            }
            *(f16x4*)(vb + off) = st;
        }
    }
}

__global__ __launch_bounds__(256, 2) void fused_iter(
    const f16* __restrict__ Wg, const f16* __restrict__ Wh,
    f16* Y, f16* v16, const f16* __restrict__ c16,
    int* flags, int ep, int last)
{
    __shared__ __align__(16) f16 As[2 * 128 * 72];   // 36.9 KB
    __shared__ __align__(16) f16 Bs[2 * 64 * 72];    // 18.4 KB (total 55.3 KB)
    const int blk = blockIdx.x;

    if (blk < 384) {   // phase-1 tile: up(j) in 0..7, rp in 0..47
        const int xcd = blk & 7, local = blk >> 3;
        const int up = local & 7, rp = xcd * 6 + (local >> 3);
        dev_p1(up * 64, rp * 64, Wg, v16, c16, Y, &flags[rp * 8 + up], As, Bs);
    }
    {                  // phase-2 tile #1 (tiles 0..511)
        const int tt = blk, xcd = tt & 7, local = tt >> 3;
        const int np = local & 15, rp = xcd * 6 + (local >> 4);
        dev_p2(np * 128, rp * 64, Wh, Y, v16, c16, &flags[rp * 8], ep, last, As, Bs);
    }
    if (blk < 256) {   // phase-2 tile #2 (tiles 512..767)
        const int tt = blk + 512, xcd = tt & 7, local = tt >> 3;
        const int np = local & 15, rp = xcd * 6 + (local >> 4);
        dev_p2(np * 128, rp * 64, Wh, Y, v16, c16, &flags[rp * 8], ep, last, As, Bs);
    }
}

extern "C" void kernel_launch(void* const* d_in, const int* in_sizes, int n_in,
                              void* d_out, int out_size, void* d_ws, size_t ws_size,
                              hipStream_t stream) {
    const float* x = (const float*)d_in[0];
    const int* idxs = (const int*)d_in[1];

    // Workspace: R5's proven ~32.8 MB envelope + flags.
    // Dg (8 MB) aliases Wg|Wh|BmY|c16-head — all dead before build_d runs.
    char* p = (char*)d_ws;
    auto take = [&](size_t n) { char* q = p; p += (n + 255) & ~(size_t)255; return q; };
    f16* Wg  = (f16*)take((size_t)MS * NF * 2);   // 2 MB
    f16* Wh  = (f16*)take((size_t)NF * MS * 2);   // 2 MB
    f16* BmY = (f16*)take((size_t)RS * MS * 2);   // 3 MB   Bm, then Y
    f16* c16 = (f16*)take((size_t)RS * NF * 2);   // 12.6 MB
    f16* v16 = (f16*)take((size_t)RS * NF * 2);   // 12.6 MB  v, then F'
    int* flags = (int*)take(2048);                // 48x8 monotone flags
    f16* Dg  = (f16*)d_ws;                        // aliased idct matrix

    hipMemsetAsync(flags, 0, 2048, stream);
    build_wb<<<dim3(RS * MS / 256), 256, 0, stream>>>(idxs, x, Wg, Wh, BmY);

    // c = 100*Bm@A; v = 0
    gemm_p<128, 128, 64, 512, 16, 3, 4, 0, 0><<<dim3(384), 256, 0, stream>>>(
        Wh, BmY, nullptr, nullptr, c16, v16, nullptr, NF);

    // 99 fused iterations (phase1 + phase2 in one launch each)
    for (int it = 0; it < 99; ++it)
        fused_iter<<<dim3(512), 256, 0, stream>>>(
            Wg, Wh, BmY, v16, c16, flags, it + 1, it == 98 ? 1 : 0);

    // out = 0.01 * F' @ D
    build_d_kernel<<<dim3(NF * NF / 256), 256, 0, stream>>>(Dg);
    gemm_p<128, 128, 64, 2048, 2, 48, 1, 1, 4><<<dim3(384), 256, 0, stream>>>(
        Dg, v16, nullptr, nullptr, nullptr, nullptr, (float*)d_out, NF);
}